// Round 2
// baseline (19310.553 us; speedup 1.0000x reference)
//
#include <hip/hip_runtime.h>
#include <math.h>

#define D 128
#define TOPK 3

// Kernel 1: per-target squared norms into workspace.
__global__ void tsq_kernel(const float* __restrict__ tgt, float* __restrict__ tsq, int M) {
    int j = blockIdx.x * blockDim.x + threadIdx.x;
    if (j >= M) return;
    const float4* t4 = reinterpret_cast<const float4*>(tgt + (size_t)j * D);
    float s0 = 0.f, s1 = 0.f, s2 = 0.f, s3 = 0.f;
#pragma unroll
    for (int k = 0; k < D / 4; ++k) {
        float4 v = t4[k];
        s0 = fmaf(v.x, v.x, s0);
        s1 = fmaf(v.y, v.y, s1);
        s2 = fmaf(v.z, v.z, s2);
        s3 = fmaf(v.w, v.w, s3);
    }
    tsq[j] = (s0 + s1) + (s2 + s3);
}

// Kernel 2: TWO threads per source row (even lane: k 0..63, odd lane: k 64..127).
// Each thread keeps its 64-float half-row in 16 float4 registers (64 VGPR).
// Partial dots combined with one __shfl_xor(.,1); top-3 tracked redundantly in
// both lanes of a pair (identical values -> no divergence). 32 rows/block of 64
// threads -> 3125 blocks -> ~12 waves/CU.
__global__ __launch_bounds__(64, 3)
void knn_topk_kernel(const float* __restrict__ src, const float* __restrict__ tgt,
                     const float* __restrict__ tsq, const float* __restrict__ tpts,
                     float* __restrict__ out, int N, int M) {
    const int tid  = (int)threadIdx.x;
    const int row  = blockIdx.x * 32 + (tid >> 1);
    const int half = tid & 1;
    const int r    = row < N ? row : (N - 1);

    const float4* s4 = reinterpret_cast<const float4*>(src + (size_t)r * D) + (half << 4);
    float4 rf[16];
#pragma unroll
    for (int k = 0; k < 16; ++k) rf[k] = s4[k];

    float d0 = INFINITY, d1 = INFINITY, d2 = INFINITY;  // d0 <= d1 <= d2
    int i0 = 0, i1 = 0, i2 = 0;

#pragma unroll 2
    for (int j = 0; j < M; ++j) {
        const float4* t4 = reinterpret_cast<const float4*>(tgt + (size_t)j * D) + (half << 4);
        float a0 = 0.f, a1 = 0.f, a2 = 0.f, a3 = 0.f;
#pragma unroll
        for (int k = 0; k < 16; ++k) {
            float4 t = t4[k];
            a0 = fmaf(rf[k].x, t.x, a0);
            a1 = fmaf(rf[k].y, t.y, a1);
            a2 = fmaf(rf[k].z, t.z, a2);
            a3 = fmaf(rf[k].w, t.w, a3);
        }
        float dp = (a0 + a1) + (a2 + a3);
        dp += __shfl_xor(dp, 1);                 // both lanes now hold the full dot
        float c = fmaf(-2.f, dp, tsq[j]);        // shifted squared distance
        if (c < d2) {
            if (c < d1) {
                d2 = d1; i2 = i1;
                if (c < d0) { d1 = d0; i1 = i0; d0 = c; i0 = j; }
                else        { d1 = c;  i1 = j; }
            } else {
                d2 = c; i2 = j;
            }
        }
    }

    if (row >= N || half != 0) return;

    // softmax over scores = -c (shift-invariant; source_sq dropped)
    float e0 = 1.f;
    float e1 = __expf(d0 - d1);
    float e2 = __expf(d0 - d2);
    float inv = 1.f / (e0 + e1 + e2);
    float w0 = e0 * inv, w1 = e1 * inv, w2 = e2 * inv;

    const float* p0 = tpts + 3 * (size_t)i0;
    const float* p1 = tpts + 3 * (size_t)i1;
    const float* p2 = tpts + 3 * (size_t)i2;
    out[3 * (size_t)row + 0] = w0 * p0[0] + w1 * p1[0] + w2 * p2[0];
    out[3 * (size_t)row + 1] = w0 * p0[1] + w1 * p1[1] + w2 * p2[1];
    out[3 * (size_t)row + 2] = w0 * p0[2] + w1 * p1[2] + w2 * p2[2];
}

extern "C" void kernel_launch(void* const* d_in, const int* in_sizes, int n_in,
                              void* d_out, int out_size, void* d_ws, size_t ws_size,
                              hipStream_t stream) {
    const float* src  = (const float*)d_in[0];  // [N,128]
    const float* tgt  = (const float*)d_in[1];  // [M,128]
    const float* tpts = (const float*)d_in[2];  // [M,3]
    float* out = (float*)d_out;

    int N = in_sizes[0] / D;
    int M = in_sizes[1] / D;

    float* tsq = (float*)d_ws;  // M floats

    tsq_kernel<<<(M + 255) / 256, 256, 0, stream>>>(tgt, tsq, M);
    int nblk = (N + 31) / 32;   // 2 threads per row, 32 rows per 64-thread block
    knn_topk_kernel<<<nblk, 64, 0, stream>>>(src, tgt, tsq, tpts, out, N, M);
}

// Round 3
// 790.511 us; speedup vs baseline: 24.4279x; 24.4279x over previous
//
#include <hip/hip_runtime.h>
#include <math.h>

#define D 128
#define CT 5                     // source col-tiles (of 16) per wave
#define SRCS_PER_WAVE (CT * 16)  // 80; 100000 = 1250 * 80 exactly

typedef __attribute__((ext_vector_type(8))) short short8;   // 8 bf16 = 4 VGPR
typedef __attribute__((ext_vector_type(4))) float f32x4;

// fp32 -> bf16 bits, round-to-nearest-even
static __device__ __forceinline__ unsigned short f2bf(float x) {
    unsigned u = __float_as_uint(x);
    unsigned r = u + 0x7FFFu + ((u >> 16) & 1u);
    return (unsigned short)(r >> 16);
}

// sorted ascending top-5 insert of packed key (smaller = closer)
static __device__ __forceinline__ void ins5(unsigned st[5], unsigned key) {
    if (key < st[4]) {
        unsigned k = key, m;
        m = k > st[3] ? k : st[3]; k = k < st[3] ? k : st[3]; st[4] = m;
        m = k > st[2] ? k : st[2]; k = k < st[2] ? k : st[2]; st[3] = m;
        m = k > st[1] ? k : st[1]; k = k < st[1] ? k : st[1]; st[2] = m;
        m = k > st[0] ? k : st[0]; k = k < st[0] ? k : st[0]; st[1] = m;
        st[0] = k;
    }
}

// Phase 0: tgt (fp32) -> tbf = bf16(-2*tgt) padded to Mpad rows (zeros),
// tsq = fp32 |t|^2 (INF for pad rows). One wave per row.
__global__ void prep_kernel(const float* __restrict__ tgt, unsigned short* __restrict__ tbf,
                            float* __restrict__ tsq, int M, int Mpad) {
    int row  = blockIdx.x;
    int lane = threadIdx.x;  // 64
    if (row >= Mpad) return;
    float2 v = make_float2(0.f, 0.f);
    if (row < M) v = *(const float2*)(tgt + (size_t)row * D + lane * 2);
    unsigned pack = (unsigned)f2bf(-2.f * v.x) | ((unsigned)f2bf(-2.f * v.y) << 16);
    *(unsigned*)(tbf + (size_t)row * D + lane * 2) = pack;
    float ss = v.x * v.x + v.y * v.y;
    #pragma unroll
    for (int off = 1; off < 64; off <<= 1) ss += __shfl_xor(ss, off);
    if (lane == 0) tsq[row] = (row < M) ? ss : __builtin_inff();
}

// Main: A = targets (rows, swept), B = sources (cols, register-resident).
// acc init = tsq[row]; MFMA adds (-2t)·s  =>  acc = shifted sq-distance.
// Per-thread per col-tile: top-5 packed keys for its row-class g = lane>>4.
// Epilogue: exact fp32 re-rank of the 20 candidates + softmax + output.
__global__ __launch_bounds__(64, 2)
void knn_kernel(const float* __restrict__ src, const unsigned short* __restrict__ tbf,
                const float* __restrict__ tsq, const float* __restrict__ tgt,
                const float* __restrict__ tpts, float* __restrict__ out,
                int N, int M, int Mpad) {
    const int lane = (int)threadIdx.x;
    const int c16  = lane & 15;   // source slot within col-tile (MFMA col)
    const int g    = lane >> 4;   // row-class (C rows 4g..4g+3)
    const int colbase = blockIdx.x * SRCS_PER_WAVE;

    // ---- build source (B) fragments: bf16, k = kk*32 + g*8 + e (matches A packing)
    short8 bfrag[CT][4];
    #pragma unroll
    for (int ct = 0; ct < CT; ++ct) {
        int srow = colbase + ct * 16 + c16;
        if (srow >= N) srow = N - 1;
        const float* sp = src + (size_t)srow * D + g * 8;
        #pragma unroll
        for (int kk = 0; kk < 4; ++kk) {
            float4 v0 = *(const float4*)(sp + kk * 32);
            float4 v1 = *(const float4*)(sp + kk * 32 + 4);
            short8 b;
            b[0] = (short)f2bf(v0.x); b[1] = (short)f2bf(v0.y);
            b[2] = (short)f2bf(v0.z); b[3] = (short)f2bf(v0.w);
            b[4] = (short)f2bf(v1.x); b[5] = (short)f2bf(v1.y);
            b[6] = (short)f2bf(v1.z); b[7] = (short)f2bf(v1.w);
            bfrag[ct][kk] = b;
        }
    }

    unsigned st[CT][5];
    #pragma unroll
    for (int ct = 0; ct < CT; ++ct)
        #pragma unroll
        for (int s = 0; s < 5; ++s) st[ct][s] = 0xFFFFFFFFu;

    const unsigned short* ap = tbf + (size_t)c16 * D + g * 8;
    const float* qp = tsq + g * 4;
    unsigned jb = (unsigned)(g * 4);
    const int steps = Mpad >> 4;

    for (int t = 0; t < steps; ++t) {
        short8 a[4];
        #pragma unroll
        for (int kk = 0; kk < 4; ++kk) a[kk] = *(const short8*)(ap + kk * 32);
        float4 qv = *(const float4*)qp;
        #pragma unroll
        for (int ct = 0; ct < CT; ++ct) {
            f32x4 acc = { qv.x, qv.y, qv.z, qv.w };
            #pragma unroll
            for (int kk = 0; kk < 4; ++kk)
                acc = __builtin_amdgcn_mfma_f32_16x16x32_bf16(a[kk], bfrag[ct][kk], acc, 0, 0, 0);
            #pragma unroll
            for (int e = 0; e < 4; ++e) {
                float c = fmaxf(acc[e], 0.0f);  // keep u32 key ordering valid
                unsigned key = (__float_as_uint(c) & 0xFFFFE000u) | (jb + (unsigned)e);
                ins5(st[ct], key);
            }
        }
        ap += 16 * D;
        qp += 16;
        jb += 16;
    }

    // ---- exact fp32 refine of 20 candidates per source ----
    __shared__ float cd[16][20];
    __shared__ int   cj[16][20];

    #pragma unroll
    for (int ct = 0; ct < CT; ++ct) {
        int js[5]; float dots[5];
        #pragma unroll
        for (int s = 0; s < 5; ++s) {
            int j = (int)(st[ct][s] & 0x1FFFu);
            js[s] = (j < M) ? j : (M - 1);
            dots[s] = 0.f;
        }
        int srow = colbase + ct * 16 + c16;
        int srcl = (srow < N) ? srow : (N - 1);
        const float* sp = src + (size_t)srcl * D;
        for (int kc = 0; kc < D / 16; ++kc) {
            float4 s0 = *(const float4*)(sp + kc * 16);
            float4 s1 = *(const float4*)(sp + kc * 16 + 4);
            float4 s2 = *(const float4*)(sp + kc * 16 + 8);
            float4 s3 = *(const float4*)(sp + kc * 16 + 12);
            #pragma unroll
            for (int s = 0; s < 5; ++s) {
                const float* tp = tgt + (size_t)js[s] * D + kc * 16;
                float4 t0 = *(const float4*)(tp);
                float4 t1 = *(const float4*)(tp + 4);
                float4 t2 = *(const float4*)(tp + 8);
                float4 t3 = *(const float4*)(tp + 12);
                float d = dots[s];
                d = fmaf(s0.x, t0.x, d); d = fmaf(s0.y, t0.y, d);
                d = fmaf(s0.z, t0.z, d); d = fmaf(s0.w, t0.w, d);
                d = fmaf(s1.x, t1.x, d); d = fmaf(s1.y, t1.y, d);
                d = fmaf(s1.z, t1.z, d); d = fmaf(s1.w, t1.w, d);
                d = fmaf(s2.x, t2.x, d); d = fmaf(s2.y, t2.y, d);
                d = fmaf(s2.z, t2.z, d); d = fmaf(s2.w, t2.w, d);
                d = fmaf(s3.x, t3.x, d); d = fmaf(s3.y, t3.y, d);
                d = fmaf(s3.z, t3.z, d); d = fmaf(s3.w, t3.w, d);
                dots[s] = d;
            }
        }
        #pragma unroll
        for (int s = 0; s < 5; ++s) {
            cd[c16][g * 5 + s] = fmaf(-2.f, dots[s], tsq[js[s]]);
            cj[c16][g * 5 + s] = js[s];
        }
        __syncthreads();
        if (g == 0) {
            float d0 = __builtin_inff(), d1 = d0, d2 = d0;
            int i0 = 0, i1 = 0, i2 = 0;
            for (int k = 0; k < 20; ++k) {
                float dd = cd[c16][k]; int jj = cj[c16][k];
                if (dd < d2) {
                    if (dd < d1) {
                        d2 = d1; i2 = i1;
                        if (dd < d0) { d1 = d0; i1 = i0; d0 = dd; i0 = jj; }
                        else         { d1 = dd; i1 = jj; }
                    } else { d2 = dd; i2 = jj; }
                }
            }
            if (srow < N) {
                float e1 = __expf(d0 - d1);
                float e2 = __expf(d0 - d2);
                float inv = 1.f / (1.f + e1 + e2);
                float w0 = inv, w1 = e1 * inv, w2 = e2 * inv;
                const float* p0 = tpts + 3 * (size_t)i0;
                const float* p1 = tpts + 3 * (size_t)i1;
                const float* p2 = tpts + 3 * (size_t)i2;
                out[3 * (size_t)srow + 0] = w0 * p0[0] + w1 * p1[0] + w2 * p2[0];
                out[3 * (size_t)srow + 1] = w0 * p0[1] + w1 * p1[1] + w2 * p2[1];
                out[3 * (size_t)srow + 2] = w0 * p0[2] + w1 * p1[2] + w2 * p2[2];
            }
        }
        __syncthreads();
    }
}

extern "C" void kernel_launch(void* const* d_in, const int* in_sizes, int n_in,
                              void* d_out, int out_size, void* d_ws, size_t ws_size,
                              hipStream_t stream) {
    const float* src  = (const float*)d_in[0];  // [N,128]
    const float* tgt  = (const float*)d_in[1];  // [M,128]
    const float* tpts = (const float*)d_in[2];  // [M,3]
    float* out = (float*)d_out;

    int N = in_sizes[0] / D;
    int M = in_sizes[1] / D;
    int Mpad = (M + 15) & ~15;

    unsigned short* tbf = (unsigned short*)d_ws;                 // Mpad*128 bf16 (-2*t)
    float* tsq = (float*)((char*)d_ws + (size_t)Mpad * D * 2);   // Mpad f32 (INF pads)

    prep_kernel<<<Mpad, 64, 0, stream>>>(tgt, tbf, tsq, M, Mpad);
    int nblk = (N + SRCS_PER_WAVE - 1) / SRCS_PER_WAVE;          // 1250
    knn_kernel<<<nblk, 64, 0, stream>>>(src, tbf, tsq, tgt, tpts, out, N, M, Mpad);
}